// Round 4
// baseline (3337.326 us; speedup 1.0000x reference)
//
#include <hip/hip_runtime.h>
#include <hip/hip_bf16.h>
#include <math.h>

// ---------------------------------------------------------------------------
// overAll_37606733644133 : relational GNN (2-layer Householder-reflection
// message passing with edge softmax) + proxy attention + gated mixing.
//
// Element dtype of float tensors is AUTO-DETECTED on device (fp32 vs bf16):
// fp32 data misread as bf16 yields Inf/NaN-exponent u16 patterns at p~1/256;
// true bf16 N(0,0.05) data yields none. All kernels dispatch on g_isf32.
//
// No d_ws usage: scratch in static __device__ globals (~5.5 MB). Feature
// storage lives in d_out ([N][768] = [ent 3x128 | rel 3x128]), fully
// overwritten each call. CSR packed: (src<<16)|rel per edge.
// ---------------------------------------------------------------------------

#define NN    50000
#define NE    800000
#define NR    2000
#define FF    128
#define FDIM  384
#define OD    768     // output row stride (2 duals x 384)
#define PP    64
#define NEPS  1e-12f

typedef unsigned short u16;
typedef unsigned int   u32;

// ---- static device scratch ------------------------------------------------
__device__ int   g_isf32;
__device__ int   g_rowptr[NN + 1];
__device__ int   g_cnt[NN];
__device__ u32   g_csr[NE];               // (src<<16) | rel
__device__ float g_relnorm[NR * FF];      // fp32 always
__device__ float g_atab[4 * NR];          // 0=ent-l0,1=ent-l1,2=rel-l0,3=rel-l1
__device__ float g_proxynT[2 * FDIM * PP];

__device__ __forceinline__ float bf2f(u16 u) {
    u32 x = ((u32)u) << 16;
    return __uint_as_float(x);
}
__device__ __forceinline__ u16 f2bf(float f) {
    u32 x = __float_as_uint(f);
    u32 r = (x + 0x7fffu + ((x >> 16) & 1u)) >> 16;  // RNE
    return (u16)r;
}
// dtype-generic accessors (idx in elements; ld2/st2 require even idx)
template <bool F32> __device__ __forceinline__ float ld1(const void* p, int i) {
    if constexpr (F32) return ((const float*)p)[i];
    else return bf2f(((const u16*)p)[i]);
}
template <bool F32> __device__ __forceinline__ float2 ld2(const void* p, int i) {
    if constexpr (F32) return *(const float2*)((const float*)p + i);
    else {
        ushort2 u = *(const ushort2*)((const u16*)p + i);
        return make_float2(bf2f(u.x), bf2f(u.y));
    }
}
template <bool F32> __device__ __forceinline__ void st1(void* p, int i, float v) {
    if constexpr (F32) ((float*)p)[i] = v;
    else ((u16*)p)[i] = f2bf(v);
}
template <bool F32> __device__ __forceinline__ void st2(void* p, int i, float a, float b) {
    if constexpr (F32) *(float2*)((float*)p + i) = make_float2(a, b);
    else *(ushort2*)((u16*)p + i) = make_ushort2(f2bf(a), f2bf(b));
}
__device__ __forceinline__ float wsum64(float v) {
#pragma unroll
    for (int m = 32; m > 0; m >>= 1) v += __shfl_xor(v, m, 64);
    return v;
}
__device__ __forceinline__ float wmax64(float v) {
#pragma unroll
    for (int m = 32; m > 0; m >>= 1) v = fmaxf(v, __shfl_xor(v, m, 64));
    return v;
}

// --- dtype detector: count bf16-Inf/NaN exponent patterns in ent_emb[0:16K]
__global__ __launch_bounds__(256) void k_detect(const u16* __restrict__ ent) {
    __shared__ int s;
    int tid = threadIdx.x;
    if (tid == 0) s = 0;
    __syncthreads();
    int c = 0;
    for (int i = tid; i < 16384; i += 256)
        c += (((ent[i] >> 7) & 0xFF) == 0xFF);
    if (c) atomicAdd(&s, c);
    __syncthreads();
    if (tid == 0) g_isf32 = (s > 0) ? 1 : 0;
}

__global__ __launch_bounds__(256) void k_zero() {
    int i = blockIdx.x * 256 + threadIdx.x;
    if (i < NN) g_cnt[i] = 0;
}

// --- relnorm[r] = l2norm(rel_emb[r]); atab[t][r] = relnorm[r].attn_t ---
template <bool F32>
__device__ void prep_rel_body(const void* rel_emb, const void* attn_e,
                              const void* attn_r) {
    int wave = threadIdx.x >> 6, lane = threadIdx.x & 63;
    int r = blockIdx.x * 4 + wave;
    if (r >= NR) return;
    float2 v = ld2<F32>(rel_emb, r * FF + 2 * lane);
    float ss = wsum64(v.x * v.x + v.y * v.y);
    float inv = 1.f / fmaxf(sqrtf(ss), NEPS);
    float rn0 = v.x * inv, rn1 = v.y * inv;
    *(float2*)(g_relnorm + r * FF + 2 * lane) = make_float2(rn0, rn1);
#pragma unroll
    for (int t = 0; t < 4; t++) {
        const void* av = (t < 2) ? attn_e : attn_r;
        int base = (t & 1) * FF + 2 * lane;
        float a0 = ld1<F32>(av, base), a1 = ld1<F32>(av, base + 1);
        float d = wsum64(rn0 * a0 + rn1 * a1);
        if (lane == 0) g_atab[t * NR + r] = d;
    }
}
__global__ __launch_bounds__(256) void k_prep_rel(const void* a, const void* b,
                                                  const void* c) {
    if (g_isf32) prep_rel_body<true>(a, b, c);
    else prep_rel_body<false>(a, b, c);
}

// --- proxynT[d][k][p] = l2norm(proxy_d[p])[k]  (transposed) ---
template <bool F32>
__device__ void prep_proxy_body(const void* proxy_e, const void* proxy_r) {
    int wave = threadIdx.x >> 6, lane = threadIdx.x & 63;
    int row = blockIdx.x * 4 + wave;  // 0..127
    if (row >= 2 * PP) return;
    int d = row >> 6, p = row & 63;
    const void* pr = (d == 0) ? proxy_e : proxy_r;
    float v[6];
    float ss = 0.f;
#pragma unroll
    for (int j = 0; j < 6; j++) {
        v[j] = ld1<F32>(pr, p * FDIM + lane + 64 * j);
        ss += v[j] * v[j];
    }
    ss = wsum64(ss);
    float inv = 1.f / fmaxf(sqrtf(ss), NEPS);
    float* ot = g_proxynT + d * FDIM * PP;
#pragma unroll
    for (int j = 0; j < 6; j++) ot[(lane + 64 * j) * PP + p] = v[j] * inv;
}
__global__ __launch_bounds__(256) void k_prep_proxy(const void* a, const void* b) {
    if (g_isf32) prep_proxy_body<true>(a, b);
    else prep_proxy_body<false>(a, b);
}

__global__ __launch_bounds__(256) void k_count(const int* __restrict__ dst) {
    int e = blockIdx.x * 256 + threadIdx.x;
    if (e < NE) atomicAdd(&g_cnt[dst[e]], 1);
}

// single-block chunked Hillis-Steele exclusive scan; also rezeros cnt
__global__ __launch_bounds__(1024) void k_scan() {
    __shared__ int s[1024];
    __shared__ int carry;
    int tid = threadIdx.x;
    if (tid == 0) carry = 0;
    __syncthreads();
    for (int base = 0; base < NN; base += 1024) {
        int i = base + tid;
        int v = (i < NN) ? g_cnt[i] : 0;
        s[tid] = v;
        __syncthreads();
        for (int off = 1; off < 1024; off <<= 1) {
            int t = (tid >= off) ? s[tid - off] : 0;
            __syncthreads();
            s[tid] += t;
            __syncthreads();
        }
        int incl = s[tid];
        int c = carry;
        if (i < NN) {
            g_rowptr[i] = c + incl - v;
            g_cnt[i] = 0;
        }
        __syncthreads();
        if (tid == 1023) carry = c + s[1023];
        __syncthreads();
    }
    if (tid == 0) g_rowptr[NN] = carry;  // == NE
}

__global__ __launch_bounds__(256) void k_fill(
    const int* __restrict__ src, const int* __restrict__ dst,
    const int* __restrict__ rel) {
    int e = blockIdx.x * 256 + threadIdx.x;
    if (e >= NE) return;
    int d = dst[e];
    int pos = atomicAdd(&g_cnt[d], 1);
    g_csr[g_rowptr[d] + pos] = ((u32)src[e] << 16) | (u32)rel[e];
}

// --- initial features: tanh(mean over incoming edges), both duals ---
template <bool F32>
__device__ void init_body(const void* ent_emb, const void* rel_emb, void* out) {
    int wave = threadIdx.x >> 6, lane = threadIdx.x & 63;
    int n = blockIdx.x * 4 + wave;
    if (n >= NN) return;
    int s0 = g_rowptr[n], s1 = g_rowptr[n + 1];
    float ae0 = 0, ae1 = 0, ar0 = 0, ar1 = 0;
    for (int idx = s0; idx < s1; idx++) {
        u32 pk = g_csr[idx];
        int s = __builtin_amdgcn_readfirstlane((int)(pk >> 16));
        int r = __builtin_amdgcn_readfirstlane((int)(pk & 0xFFFFu));
        float2 ue = ld2<F32>(ent_emb, s * FF + 2 * lane);
        float2 ur = ld2<F32>(rel_emb, r * FF + 2 * lane);
        ae0 += ue.x; ae1 += ue.y;
        ar0 += ur.x; ar1 += ur.y;
    }
    float invd = 1.f / (float)max(s1 - s0, 1);
    st2<F32>(out, n * OD + 2 * lane, tanhf(ae0 * invd), tanhf(ae1 * invd));
    st2<F32>(out, n * OD + FDIM + 2 * lane, tanhf(ar0 * invd), tanhf(ar1 * invd));
}
__global__ __launch_bounds__(256) void k_init(const void* a, const void* b, void* o) {
    if (g_isf32) init_body<true>(a, b, o);
    else init_body<false>(a, b, o);
}

// --- one message-passing layer: wave per node, edge-softmax + Householder ---
template <bool F32>
__device__ void layer_body(void* buf, int base_in, int base_out, int t) {
    int wave = threadIdx.x >> 6, lane = threadIdx.x & 63;
    int n = blockIdx.x * 4 + wave;
    if (n >= NN) return;
    const float* atab = g_atab + t * NR;
    int s0 = g_rowptr[n], s1 = g_rowptr[n + 1];
    int oidx = n * OD + base_out + 2 * lane;
    if (s1 == s0) {
        st2<F32>(buf, oidx, 0.f, 0.f);
        return;
    }
    float am = -1e30f;
    for (int idx = s0 + lane; idx < s1; idx += 64)
        am = fmaxf(am, atab[g_csr[idx] & 0xFFFFu]);
    am = wmax64(am);
    float acc0 = 0.f, acc1 = 0.f, ws = 0.f;
    for (int idx = s0; idx < s1; idx++) {
        u32 pk = g_csr[idx];
        int s = __builtin_amdgcn_readfirstlane((int)(pk >> 16));
        int r = __builtin_amdgcn_readfirstlane((int)(pk & 0xFFFFu));
        float2 h = ld2<F32>(buf, s * OD + base_in + 2 * lane);
        float2 rn = *(const float2*)(g_relnorm + r * FF + 2 * lane);
        float dot = wsum64(h.x * rn.x + h.y * rn.y);
        float w = expf(atab[r] - am);
        ws += w;
        acc0 += w * (h.x - 2.f * dot * rn.x);
        acc1 += w * (h.y - 2.f * dot * rn.y);
    }
    float inv = 1.f / ws;
    st2<F32>(buf, oidx, tanhf(acc0 * inv), tanhf(acc1 * inv));
}
__global__ __launch_bounds__(256) void k_layer(void* buf, int bi, int bo, int t) {
    if (g_isf32) layer_body<true>(buf, bi, bo, t);
    else layer_body<false>(buf, bi, bo, t);
}

// --- fused proxy attention + gate: 16 nodes per block ---
// pf = o - softmax(l2n(o) @ l2n(proxy)^T) @ proxy     (kept in LDS)
// out = g*o + (1-g)*pf,  g = sigmoid(pf @ W + bias)   (in-place over o)
template <bool F32>
__device__ void pg_body(void* out, const void* proxy, const void* W,
                        const void* bias, int dual) {
    __shared__ float o_s[16 * FDIM];  // o, then pf in place (24 KB)
    __shared__ float W_s[16 * FDIM];  // W k-tile (24 KB)
    __shared__ float att_s[16][PP];
    __shared__ float invn_s[16];
    int tid = threadIdx.x;
    int n0 = blockIdx.x * 16;
    int dual_off = dual * FDIM;
    const float* proxynT = g_proxynT + dual * FDIM * PP;
    int lane = tid & 63, g = tid >> 6;
    for (int i = 2 * tid; i < 16 * FDIM; i += 512) {
        int n = i / FDIM, c = i - n * FDIM;
        float2 u = ld2<F32>(out, (n0 + n) * OD + dual_off + c);
        o_s[i] = u.x;
        o_s[i + 1] = u.y;
    }
    __syncthreads();
#pragma unroll
    for (int j = 0; j < 4; j++) {  // 1/||o|| per node (wave g owns g+4j)
        int n = g + 4 * j;
        float ss = 0.f;
#pragma unroll
        for (int q = 0; q < 6; q++) {
            float v = o_s[n * FDIM + lane + 64 * q];
            ss += v * v;
        }
        ss = wsum64(ss);
        if (lane == 0) invn_s[n] = 1.f / fmaxf(sqrtf(ss), NEPS);
    }
    __syncthreads();
    {  // logits: lane = proxy row p
        float acc[4] = {0.f, 0.f, 0.f, 0.f};
        for (int k = 0; k < FDIM; k++) {
            float w = proxynT[k * PP + lane];
#pragma unroll
            for (int j = 0; j < 4; j++) acc[j] += o_s[(g + 4 * j) * FDIM + k] * w;
        }
#pragma unroll
        for (int j = 0; j < 4; j++) {
            int n = g + 4 * j;
            att_s[n][lane] = acc[j] * invn_s[n];
        }
    }
    __syncthreads();
#pragma unroll
    for (int j = 0; j < 4; j++) {  // softmax over P=64
        int n = g + 4 * j;
        float l = att_s[n][lane];
        float m = wmax64(l);
        float e = expf(l - m);
        float s = wsum64(e);
        att_s[n][lane] = e / s;
    }
    __syncthreads();
    // pf = o - att @ proxy, in place
    for (int f = tid; f < FDIM; f += 256) {
        float acc[16];
#pragma unroll
        for (int n = 0; n < 16; n++) acc[n] = 0.f;
        for (int p = 0; p < PP; p++) {
            float w = ld1<F32>(proxy, p * FDIM + f);
#pragma unroll
            for (int n = 0; n < 16; n++) acc[n] += att_s[n][p] * w;
        }
#pragma unroll
        for (int n = 0; n < 16; n++) o_s[n * FDIM + f] -= acc[n];
    }
    __syncthreads();
    // gate GEMM: thread (g,lane) owns nodes g*4..g*4+3, f = lane+64j
    float acc2[4][6];
#pragma unroll
    for (int i = 0; i < 4; i++)
#pragma unroll
        for (int j = 0; j < 6; j++) acc2[i][j] = 0.f;
    for (int k0 = 0; k0 < FDIM; k0 += 16) {
        for (int i = 2 * tid; i < 16 * FDIM; i += 512) {
            float2 u = ld2<F32>(W, k0 * FDIM + i);
            W_s[i] = u.x;
            W_s[i + 1] = u.y;
        }
        __syncthreads();
#pragma unroll
        for (int k = 0; k < 16; k++) {
            float a[4];  // g wave-uniform -> LDS broadcast
#pragma unroll
            for (int i = 0; i < 4; i++) a[i] = o_s[(g * 4 + i) * FDIM + k0 + k];
#pragma unroll
            for (int j = 0; j < 6; j++) {
                float w = W_s[k * FDIM + lane + 64 * j];
#pragma unroll
                for (int i = 0; i < 4; i++) acc2[i][j] += a[i] * w;
            }
        }
        __syncthreads();
    }
#pragma unroll
    for (int j = 0; j < 6; j++) {
        int f = lane + 64 * j;
        float b = ld1<F32>(bias, f);
#pragma unroll
        for (int i = 0; i < 4; i++) {
            int nl = g * 4 + i;
            int n = n0 + nl;
            float lin = acc2[i][j] + b;
            float gt = 1.f / (1.f + expf(-lin));
            float o = ld1<F32>(out, n * OD + dual_off + f);  // own elem
            float pv = o_s[nl * FDIM + f];
            st1<F32>(out, n * OD + dual_off + f, gt * o + (1.f - gt) * pv);
        }
    }
}
__global__ __launch_bounds__(256) void k_pg(void* out, const void* proxy,
                                            const void* W, const void* bias,
                                            int dual) {
    if (g_isf32) pg_body<true>(out, proxy, W, bias, dual);
    else pg_body<false>(out, proxy, W, bias, dual);
}

extern "C" void kernel_launch(void* const* d_in, const int* in_sizes, int n_in,
                              void* d_out, int out_size, void* d_ws, size_t ws_size,
                              hipStream_t stream) {
    const void* ent_emb = d_in[0];
    const void* rel_emb = d_in[1];
    const int* e_src    = (const int*)d_in[2];
    const int* e_dst    = (const int*)d_in[3];
    const int* e_rel    = (const int*)d_in[4];
    const void* attn_e  = d_in[5];
    const void* gate_e  = d_in[6];
    const void* proxy_e = d_in[7];
    const void* bias_e  = d_in[8];
    const void* attn_r  = d_in[9];
    const void* gate_r  = d_in[10];
    const void* proxy_r = d_in[11];
    const void* bias_r  = d_in[12];
    void* out = d_out;
    (void)d_ws; (void)ws_size; (void)in_sizes; (void)n_in; (void)out_size;

    k_detect<<<1, 256, 0, stream>>>((const u16*)ent_emb);
    k_zero<<<(NN + 255) / 256, 256, 0, stream>>>();
    k_prep_rel<<<(NR + 3) / 4, 256, 0, stream>>>(rel_emb, attn_e, attn_r);
    k_prep_proxy<<<32, 256, 0, stream>>>(proxy_e, proxy_r);
    k_count<<<(NE + 255) / 256, 256, 0, stream>>>(e_dst);
    k_scan<<<1, 1024, 0, stream>>>();
    k_fill<<<(NE + 255) / 256, 256, 0, stream>>>(e_src, e_dst, e_rel);
    k_init<<<NN / 4, 256, 0, stream>>>(ent_emb, rel_emb, out);
    // ent: cols 0..383 ; rel: cols 384..767 (each = [l0|l1|l2] x 128)
    k_layer<<<NN / 4, 256, 0, stream>>>(out, 0, FF, 0);
    k_layer<<<NN / 4, 256, 0, stream>>>(out, FF, 2 * FF, 1);
    k_layer<<<NN / 4, 256, 0, stream>>>(out, FDIM, FDIM + FF, 2);
    k_layer<<<NN / 4, 256, 0, stream>>>(out, FDIM + FF, FDIM + 2 * FF, 3);
    k_pg<<<NN / 16, 256, 0, stream>>>(out, proxy_e, gate_e, bias_e, 0);
    k_pg<<<NN / 16, 256, 0, stream>>>(out, proxy_r, gate_r, bias_r, 1);
}

// Round 5
// 1690.220 us; speedup vs baseline: 1.9745x; 1.9745x over previous
//
#include <hip/hip_runtime.h>
#include <math.h>

// ---------------------------------------------------------------------------
// overAll_37606733644133 : relational GNN (2-layer Householder-reflection
// message passing with edge softmax) + proxy attention + gated mixing.
// All float tensors are fp32 (verified round 4: dtype detector selected fp32,
// absmax 2.4e-4; the "bf16" in the harness label is a hardcoded string).
//
// Scratch in static __device__ globals (~5.5 MB); no d_ws usage. Feature
// storage lives in d_out ([N][768] fp32 = [ent 3x128 | rel 3x128]), fully
// overwritten each call. CSR packed: (src<<16)|rel per edge.
// k_pg: LDS kept to ~28 KB (5 blocks/CU); W read direct from global (L1/L2).
// ---------------------------------------------------------------------------

#define NN    50000
#define NE    800000
#define NR    2000
#define FF    128
#define FDIM  384
#define OD    768     // output row stride (2 duals x 384)
#define PP    64
#define NEPS  1e-12f

typedef unsigned int u32;

// ---- static device scratch ------------------------------------------------
__device__ int   g_rowptr[NN + 1];
__device__ int   g_cnt[NN];
__device__ u32   g_csr[NE];               // (src<<16) | rel
__device__ float g_relnorm[NR * FF];
__device__ float g_atab[4 * NR];          // 0=ent-l0,1=ent-l1,2=rel-l0,3=rel-l1
__device__ float g_proxynT[2 * FDIM * PP];

__device__ __forceinline__ float wsum64(float v) {
#pragma unroll
    for (int m = 32; m > 0; m >>= 1) v += __shfl_xor(v, m, 64);
    return v;
}
__device__ __forceinline__ float wmax64(float v) {
#pragma unroll
    for (int m = 32; m > 0; m >>= 1) v = fmaxf(v, __shfl_xor(v, m, 64));
    return v;
}

__global__ __launch_bounds__(256) void k_zero() {
    int i = blockIdx.x * 256 + threadIdx.x;
    if (i < NN) g_cnt[i] = 0;
}

// --- relnorm[r] = l2norm(rel_emb[r]); atab[t][r] = relnorm[r].attn_t ---
__global__ __launch_bounds__(256) void k_prep_rel(
    const float* __restrict__ rel_emb, const float* __restrict__ attn_e,
    const float* __restrict__ attn_r) {
    int wave = threadIdx.x >> 6, lane = threadIdx.x & 63;
    int r = blockIdx.x * 4 + wave;
    if (r >= NR) return;
    float2 v = *(const float2*)(rel_emb + r * FF + 2 * lane);
    float ss = wsum64(v.x * v.x + v.y * v.y);
    float inv = 1.f / fmaxf(sqrtf(ss), NEPS);
    float rn0 = v.x * inv, rn1 = v.y * inv;
    *(float2*)(g_relnorm + r * FF + 2 * lane) = make_float2(rn0, rn1);
#pragma unroll
    for (int t = 0; t < 4; t++) {
        const float* av = ((t < 2) ? attn_e : attn_r) + (t & 1) * FF + 2 * lane;
        float d = wsum64(rn0 * av[0] + rn1 * av[1]);
        if (lane == 0) g_atab[t * NR + r] = d;
    }
}

// --- proxynT[d][k][p] = l2norm(proxy_d[p])[k]  (transposed) ---
__global__ __launch_bounds__(256) void k_prep_proxy(
    const float* __restrict__ proxy_e, const float* __restrict__ proxy_r) {
    int wave = threadIdx.x >> 6, lane = threadIdx.x & 63;
    int row = blockIdx.x * 4 + wave;  // 0..127
    if (row >= 2 * PP) return;
    int d = row >> 6, p = row & 63;
    const float* pr = ((d == 0) ? proxy_e : proxy_r) + p * FDIM;
    float v[6];
    float ss = 0.f;
#pragma unroll
    for (int j = 0; j < 6; j++) {
        v[j] = pr[lane + 64 * j];
        ss += v[j] * v[j];
    }
    ss = wsum64(ss);
    float inv = 1.f / fmaxf(sqrtf(ss), NEPS);
    float* ot = g_proxynT + d * FDIM * PP;
#pragma unroll
    for (int j = 0; j < 6; j++) ot[(lane + 64 * j) * PP + p] = v[j] * inv;
}

__global__ __launch_bounds__(256) void k_count(const int* __restrict__ dst) {
    int e = blockIdx.x * 256 + threadIdx.x;
    if (e < NE) atomicAdd(&g_cnt[dst[e]], 1);
}

// single-block chunked Hillis-Steele exclusive scan; also rezeros cnt
__global__ __launch_bounds__(1024) void k_scan() {
    __shared__ int s[1024];
    __shared__ int carry;
    int tid = threadIdx.x;
    if (tid == 0) carry = 0;
    __syncthreads();
    for (int base = 0; base < NN; base += 1024) {
        int i = base + tid;
        int v = (i < NN) ? g_cnt[i] : 0;
        s[tid] = v;
        __syncthreads();
        for (int off = 1; off < 1024; off <<= 1) {
            int t = (tid >= off) ? s[tid - off] : 0;
            __syncthreads();
            s[tid] += t;
            __syncthreads();
        }
        int incl = s[tid];
        int c = carry;
        if (i < NN) {
            g_rowptr[i] = c + incl - v;
            g_cnt[i] = 0;
        }
        __syncthreads();
        if (tid == 1023) carry = c + s[1023];
        __syncthreads();
    }
    if (tid == 0) g_rowptr[NN] = carry;  // == NE
}

__global__ __launch_bounds__(256) void k_fill(
    const int* __restrict__ src, const int* __restrict__ dst,
    const int* __restrict__ rel) {
    int e = blockIdx.x * 256 + threadIdx.x;
    if (e >= NE) return;
    int d = dst[e];
    int pos = atomicAdd(&g_cnt[d], 1);
    g_csr[g_rowptr[d] + pos] = ((u32)src[e] << 16) | (u32)rel[e];
}

// --- initial features: tanh(mean over incoming edges), both duals ---
__global__ __launch_bounds__(256) void k_init(
    const float* __restrict__ ent_emb, const float* __restrict__ rel_emb,
    float* __restrict__ out) {
    int wave = threadIdx.x >> 6, lane = threadIdx.x & 63;
    int n = blockIdx.x * 4 + wave;
    if (n >= NN) return;
    int s0 = g_rowptr[n], s1 = g_rowptr[n + 1];
    float ae0 = 0, ae1 = 0, ar0 = 0, ar1 = 0;
    for (int idx = s0; idx < s1; idx++) {
        u32 pk = g_csr[idx];
        int s = __builtin_amdgcn_readfirstlane((int)(pk >> 16));
        int r = __builtin_amdgcn_readfirstlane((int)(pk & 0xFFFFu));
        float2 ue = *(const float2*)(ent_emb + s * FF + 2 * lane);
        float2 ur = *(const float2*)(rel_emb + r * FF + 2 * lane);
        ae0 += ue.x; ae1 += ue.y;
        ar0 += ur.x; ar1 += ur.y;
    }
    float invd = 1.f / (float)max(s1 - s0, 1);
    *(float2*)(out + n * OD + 2 * lane) =
        make_float2(tanhf(ae0 * invd), tanhf(ae1 * invd));
    *(float2*)(out + n * OD + FDIM + 2 * lane) =
        make_float2(tanhf(ar0 * invd), tanhf(ar1 * invd));
}

// --- one message-passing layer: wave per node, edge-softmax + Householder ---
// blockIdx.y = dual (0=ent cols 0..383, 1=rel cols 384..767); layer in {0,1}
__global__ __launch_bounds__(256) void k_layer(float* buf, int layer) {
    int wave = threadIdx.x >> 6, lane = threadIdx.x & 63;
    int n = blockIdx.x * 4 + wave;
    if (n >= NN) return;
    int dual = blockIdx.y;
    int base_in = dual * FDIM + layer * FF;
    int base_out = base_in + FF;
    int t = dual * 2 + layer;
    const float* atab = g_atab + t * NR;
    int s0 = g_rowptr[n], s1 = g_rowptr[n + 1];
    float* outp = buf + n * OD + base_out + 2 * lane;
    if (s1 == s0) {
        *(float2*)outp = make_float2(0.f, 0.f);
        return;
    }
    float am = -1e30f;
    for (int idx = s0 + lane; idx < s1; idx += 64)
        am = fmaxf(am, atab[g_csr[idx] & 0xFFFFu]);
    am = wmax64(am);
    float acc0 = 0.f, acc1 = 0.f, ws = 0.f;
    for (int idx = s0; idx < s1; idx++) {
        u32 pk = g_csr[idx];
        int s = __builtin_amdgcn_readfirstlane((int)(pk >> 16));
        int r = __builtin_amdgcn_readfirstlane((int)(pk & 0xFFFFu));
        float2 h = *(const float2*)(buf + s * OD + base_in + 2 * lane);
        float2 rn = *(const float2*)(g_relnorm + r * FF + 2 * lane);
        float dot = wsum64(h.x * rn.x + h.y * rn.y);
        float w = expf(atab[r] - am);
        ws += w;
        acc0 += w * (h.x - 2.f * dot * rn.x);
        acc1 += w * (h.y - 2.f * dot * rn.y);
    }
    float inv = 1.f / ws;
    *(float2*)outp = make_float2(tanhf(acc0 * inv), tanhf(acc1 * inv));
}

// --- fused proxy attention + gate: 16 nodes per block, blockIdx.y = dual ---
// pf = o - softmax(l2n(o) @ l2n(proxy)^T) @ proxy     (kept in LDS)
// out = g*o + (1-g)*pf,  g = sigmoid(pf @ W + bias)   (in-place over o)
// LDS ~28.1 KB -> 5 blocks/CU; W read direct from global (L1/L2-resident).
__global__ __launch_bounds__(256) void k_pg(
    float* out, const float* __restrict__ proxy_e,
    const float* __restrict__ proxy_r, const float* __restrict__ gate_e,
    const float* __restrict__ gate_r, const float* __restrict__ bias_e,
    const float* __restrict__ bias_r) {
    __shared__ float o_s[16 * FDIM];   // o, then pf in place (24 KB)
    __shared__ float att_s[16][PP];    // 4 KB
    __shared__ float invn_s[16];
    int tid = threadIdx.x;
    int n0 = blockIdx.x * 16;
    int dual = blockIdx.y;
    int dual_off = dual * FDIM;
    const float* proxy = dual ? proxy_r : proxy_e;
    const float* W     = dual ? gate_r : gate_e;
    const float* bias  = dual ? bias_r : bias_e;
    const float* proxynT = g_proxynT + dual * FDIM * PP;
    int lane = tid & 63, g = tid >> 6;
    // stage o via float4 (row base is 384-aligned)
    for (int i4 = tid; i4 < 16 * (FDIM / 4); i4 += 256) {
        int n = i4 / (FDIM / 4), c4 = i4 - n * (FDIM / 4);
        float4 u = *(const float4*)(out + (n0 + n) * OD + dual_off + 4 * c4);
        *(float4*)(o_s + n * FDIM + 4 * c4) = u;
    }
    __syncthreads();
#pragma unroll
    for (int j = 0; j < 4; j++) {  // 1/||o|| per node (wave g owns g+4j)
        int n = g + 4 * j;
        float ss = 0.f;
#pragma unroll
        for (int q = 0; q < 6; q++) {
            float v = o_s[n * FDIM + lane + 64 * q];
            ss += v * v;
        }
        ss = wsum64(ss);
        if (lane == 0) invn_s[n] = 1.f / fmaxf(sqrtf(ss), NEPS);
    }
    __syncthreads();
    {  // logits: lane = proxy row p
        float acc[4] = {0.f, 0.f, 0.f, 0.f};
        for (int k = 0; k < FDIM; k++) {
            float w = proxynT[k * PP + lane];
#pragma unroll
            for (int j = 0; j < 4; j++) acc[j] += o_s[(g + 4 * j) * FDIM + k] * w;
        }
#pragma unroll
        for (int j = 0; j < 4; j++) {
            int n = g + 4 * j;
            att_s[n][lane] = acc[j] * invn_s[n];
        }
    }
    __syncthreads();
#pragma unroll
    for (int j = 0; j < 4; j++) {  // softmax over P=64
        int n = g + 4 * j;
        float l = att_s[n][lane];
        float m = wmax64(l);
        float e = expf(l - m);
        float s = wsum64(e);
        att_s[n][lane] = e / s;
    }
    __syncthreads();
    // pf = o - att @ proxy, in place
    for (int f = tid; f < FDIM; f += 256) {
        float acc[16];
#pragma unroll
        for (int n = 0; n < 16; n++) acc[n] = 0.f;
        for (int p = 0; p < PP; p++) {
            float w = proxy[p * FDIM + f];
#pragma unroll
            for (int n = 0; n < 16; n++) acc[n] += att_s[n][p] * w;
        }
#pragma unroll
        for (int n = 0; n < 16; n++) o_s[n * FDIM + f] -= acc[n];
    }
    __syncthreads();
    // gate GEMM: thread (g,lane) owns nodes g*4..g*4+3, f = lane+64j
    // W from global (L1-dedup across waves), pf from LDS (wave-uniform bcast)
    float acc2[4][6];
#pragma unroll
    for (int i = 0; i < 4; i++)
#pragma unroll
        for (int j = 0; j < 6; j++) acc2[i][j] = 0.f;
#pragma unroll 2
    for (int k = 0; k < FDIM; k++) {
        float a[4];
#pragma unroll
        for (int i = 0; i < 4; i++) a[i] = o_s[(g * 4 + i) * FDIM + k];
        float w[6];
#pragma unroll
        for (int j = 0; j < 6; j++) w[j] = W[k * FDIM + lane + 64 * j];
#pragma unroll
        for (int j = 0; j < 6; j++)
#pragma unroll
            for (int i = 0; i < 4; i++) acc2[i][j] += a[i] * w[j];
    }
#pragma unroll
    for (int j = 0; j < 6; j++) {
        int f = lane + 64 * j;
        float b = bias[f];
#pragma unroll
        for (int i = 0; i < 4; i++) {
            int nl = g * 4 + i;
            int n = n0 + nl;
            float lin = acc2[i][j] + b;
            float gt = 1.f / (1.f + expf(-lin));
            float o = out[n * OD + dual_off + f];  // own elem: read then write
            float pv = o_s[nl * FDIM + f];
            out[n * OD + dual_off + f] = gt * o + (1.f - gt) * pv;
        }
    }
}

extern "C" void kernel_launch(void* const* d_in, const int* in_sizes, int n_in,
                              void* d_out, int out_size, void* d_ws, size_t ws_size,
                              hipStream_t stream) {
    const float* ent_emb = (const float*)d_in[0];
    const float* rel_emb = (const float*)d_in[1];
    const int* e_src     = (const int*)d_in[2];
    const int* e_dst     = (const int*)d_in[3];
    const int* e_rel     = (const int*)d_in[4];
    const float* attn_e  = (const float*)d_in[5];
    const float* gate_e  = (const float*)d_in[6];
    const float* proxy_e = (const float*)d_in[7];
    const float* bias_e  = (const float*)d_in[8];
    const float* attn_r  = (const float*)d_in[9];
    const float* gate_r  = (const float*)d_in[10];
    const float* proxy_r = (const float*)d_in[11];
    const float* bias_r  = (const float*)d_in[12];
    float* out = (float*)d_out;
    (void)d_ws; (void)ws_size; (void)in_sizes; (void)n_in; (void)out_size;

    k_zero<<<(NN + 255) / 256, 256, 0, stream>>>();
    k_prep_rel<<<NR / 4, 256, 0, stream>>>(rel_emb, attn_e, attn_r);
    k_prep_proxy<<<32, 256, 0, stream>>>(proxy_e, proxy_r);
    k_count<<<(NE + 255) / 256, 256, 0, stream>>>(e_dst);
    k_scan<<<1, 1024, 0, stream>>>();
    k_fill<<<(NE + 255) / 256, 256, 0, stream>>>(e_src, e_dst, e_rel);
    k_init<<<NN / 4, 256, 0, stream>>>(ent_emb, rel_emb, out);
    k_layer<<<dim3(NN / 4, 2), 256, 0, stream>>>(out, 0);
    k_layer<<<dim3(NN / 4, 2), 256, 0, stream>>>(out, 1);
    k_pg<<<dim3(NN / 16, 2), 256, 0, stream>>>(out, proxy_e, proxy_r,
                                               gate_e, gate_r, bias_e, bias_r);
}